// Round 11
// baseline (135.371 us; speedup 1.0000x reference)
//
#include <hip/hip_runtime.h>
#include <stdint.h>

// Problem constants (GPT-2 attention block)
#define S_LEN  2048
#define EMBD   1024
#define NHEAD  16
#define HDIM   64
#define BATCHN 2
#define ROWS   (BATCHN * S_LEN)   // 4096 = flattened B*S

using bf16x8 = __attribute__((ext_vector_type(8))) __bf16;
using f32x4  = __attribute__((ext_vector_type(4))) float;
using f32x16 = __attribute__((ext_vector_type(16))) float;
using u32x4  = __attribute__((ext_vector_type(4))) unsigned;

typedef const __attribute__((address_space(1))) void* gas_ptr;
typedef __attribute__((address_space(3)))       void* las_ptr;

// Async global->LDS, 16B per lane. LDS dest = wave-uniform base + lane*16.
__device__ __forceinline__ void load_lds16(const void* g, void* l) {
    __builtin_amdgcn_global_load_lds((gas_ptr)(uintptr_t)g, (las_ptr)(uintptr_t)l, 16, 0, 0);
}

// fp32 -> bf16 round-to-nearest-even
__device__ __forceinline__ unsigned short f2bf(float f) {
    unsigned u = __builtin_bit_cast(unsigned, f);
    u += 0x7fffu + ((u >> 16) & 1u);
    return (unsigned short)(u >> 16);
}

// pack 2 floats -> 1 dword of 2 bf16 (lo = a, hi = b); hw cvt_pk (no builtin)
__device__ __forceinline__ unsigned pkbf(float a, float b) {
    unsigned r;
    asm("v_cvt_pk_bf16_f32 %0, %1, %2" : "=v"(r) : "v"(a), "v"(b));
    return r;
}

// XOR-swizzled element offset within a [R][64] bf16 tile (16B-chunk XOR row&7).
// Fixes the 16-way ds_read_b128 bank conflict of 128B-stride rows (T2).
__device__ __forceinline__ int swz(int row, int ebase) {
    int byte = (row << 7) + (ebase << 1);
    byte ^= (row & 7) << 4;
    return byte >> 1;
}

// Merged fp32->bf16 convert for 3 sources; destinations are contiguous in ws.
__global__ void cvt3_f32_bf16(const float* __restrict__ s0,
                              const float* __restrict__ s1,
                              const float* __restrict__ s2,
                              unsigned short* __restrict__ d,
                              int n0, int n01, int ntot) {
    int i = blockIdx.x * blockDim.x + threadIdx.x;
    int stride = gridDim.x * blockDim.x;
    for (int idx = i * 4; idx < ntot; idx += stride * 4) {
        const float* s; int off;
        if (idx < n0)       { s = s0; off = idx; }
        else if (idx < n01) { s = s1; off = idx - n0; }
        else                { s = s2; off = idx - n01; }
        float4 f = *(const float4*)(s + off);
        uint2 p;
        p.x = (unsigned)f2bf(f.x) | ((unsigned)f2bf(f.y) << 16);
        p.y = (unsigned)f2bf(f.z) | ((unsigned)f2bf(f.w) << 16);
        *(uint2*)(d + idx) = p;
    }
}

// ---------------------------------------------------------------------------
// bf16 GEMM, C[m][n] = sum_k A[m][k]*B[n][k] (+bias[n]).  A:[M][K] B:[N][K]
// 128x128 tile, BK=64, 4 waves (2x2), each wave 64x64 via 16x16x32 MFMA.
// LDS tiles XOR-swizzled (T2): pre-swizzled global source + swz() reads —
// R9->R10 dropped conflicts 9.4e6 -> off the chart and total by 17.6 us.
// MODE 0: write fp32 C[m*N+n] (+bias)                 (output projection)
// MODE 1: scatter bf16 q(pre-scaled)/k [B,H,S,D], V^T [B,H,D,S]  (QKV)
// ---------------------------------------------------------------------------
#define SCALE_Q 0.18033688011112042f   // 0.125 * log2(e): softmax in exp2 domain

template <int MODE>
__global__ __launch_bounds__(256) void gemm_bt(
    const unsigned short* __restrict__ A, const unsigned short* __restrict__ B,
    const float* __restrict__ bias, float* __restrict__ Cout,
    unsigned short* __restrict__ qb, unsigned short* __restrict__ kb,
    unsigned short* __restrict__ vb, int M, int N, int K)
{
    __shared__ __align__(16) unsigned short sA[128 * 64];
    __shared__ __align__(16) unsigned short sB[128 * 64];

    const int tid  = threadIdx.x;
    const int wid  = tid >> 6;
    const int lane = tid & 63;
    const int g    = lane >> 4;       // 0..3
    const int c    = lane & 15;       // 0..15
    const int bm   = blockIdx.x * 128;
    const int bn   = blockIdx.y * 128;
    const int wm   = (wid >> 1) * 64;
    const int wn   = (wid & 1) * 64;

    f32x4 acc[4][4] = {};

    for (int k0 = 0; k0 < K; k0 += 64) {
        // stage: pre-swizzled global source, linear LDS dest (rule #21)
#pragma unroll
        for (int i = 0; i < 4; ++i) {
            int cidx = i * 256 + tid;            // 16B chunk index in tile
            int row  = cidx >> 3;
            int col  = ((cidx & 7) ^ (row & 7)) << 3;
            load_lds16(A + (size_t)(bm + row) * K + k0 + col,
                       &sA[i * 2048 + wid * 512]);
            load_lds16(B + (size_t)(bn + row) * K + k0 + col,
                       &sB[i * 2048 + wid * 512]);
        }
        __syncthreads();
#pragma unroll
        for (int kk = 0; kk < 2; ++kk) {
            bf16x8 af[4], bfr[4];
#pragma unroll
            for (int i = 0; i < 4; ++i)
                af[i] = *(const bf16x8*)&sA[swz(wm + i * 16 + c, kk * 32 + g * 8)];
#pragma unroll
            for (int j = 0; j < 4; ++j)
                bfr[j] = *(const bf16x8*)&sB[swz(wn + j * 16 + c, kk * 32 + g * 8)];
#pragma unroll
            for (int i = 0; i < 4; ++i)
#pragma unroll
                for (int j = 0; j < 4; ++j)
                    acc[i][j] = __builtin_amdgcn_mfma_f32_16x16x32_bf16(
                        af[i], bfr[j], acc[i][j], 0, 0, 0);
        }
        __syncthreads();
    }

#pragma unroll
    for (int i = 0; i < 4; ++i)
#pragma unroll
        for (int j = 0; j < 4; ++j) {
            int n = bn + wn + j * 16 + c;
            float bv = bias[n];
            if (MODE == 0) {
#pragma unroll
                for (int r = 0; r < 4; ++r) {
                    int m = bm + wm + i * 16 + g * 4 + r;
                    Cout[(size_t)m * N + n] = acc[i][j][r] + bv;
                }
            } else {
                int which = n >> 10, h = (n & 1023) >> 6, d = n & 63;
                if (which < 2) {
                    unsigned short* dst = (which == 0) ? qb : kb;
                    float sc = (which == 0) ? SCALE_Q : 1.0f;
#pragma unroll
                    for (int r = 0; r < 4; ++r) {
                        int m = bm + wm + i * 16 + g * 4 + r;
                        int b = m >> 11, s = m & 2047;
                        dst[(((size_t)b * NHEAD + h) * S_LEN + s) * HDIM + d] =
                            f2bf((acc[i][j][r] + bv) * sc);
                    }
                } else {
                    // V^T [B,H,D,S]: pack 4 consecutive s into one 8B store
                    int m0 = bm + wm + i * 16 + g * 4;
                    int b = m0 >> 11, s0 = m0 & 2047;
                    uint2 p;
                    p.x = pkbf(acc[i][j][0] + bv, acc[i][j][1] + bv);
                    p.y = pkbf(acc[i][j][2] + bv, acc[i][j][3] + bv);
                    *(uint2*)&vb[(((size_t)b * NHEAD + h) * HDIM + d) * S_LEN + s0] = p;
                }
            }
        }
}

// ---------------------------------------------------------------------------
// Flash-style causal attention — 32x32 MFMA structure (m214-class).
// Grid: 512 blocks x 256 thr (4 waves). Wave owns 32 q-rows; block = 128 q.
//
// CO-RESIDENCY MODEL (R10 post-mortem): all 512 blocks fit simultaneously
// (48KB LDS -> 2 blocks/CU); there is NO dynamic dispatch. Makespan = max
// over CUs of the sum of its 2 resident blocks' tile counts. Evidence: R9
// (LPT) and R10 (x/x+256 pairing) produced bit-identical attn times — both
// give ADJACENT blocks the same s, so consecutive-fill pairs two heavy
// blocks (worst CU = 64 tiles). Fix: adjacent blocks complementary:
//   p = x>>1, e = x&1:  bh = p>>3,  j = p&7,  s = e ? j : 15-j
// -> every consecutive pair sums to 34 tiles AND shares bh (K/V L1 reuse).
//
// Swapped QK^T (D[kv][q=lane&31]); q-row owned by a hi-lane pair (lane^32).
// K and V^T co-staged into swizzled LDS (3-buffer, counted vmcnt(4), one
// barrier/tile). P stays IN REGISTERS: cvt_pk pairs + 4 shfl_xor(32) + hi-
// selects per 16-kv slice build the PV B-fragment (no LDS round-trip).
// 32x32x16 layouts (m74/m101/m89-verified):
//   A/B: row|col = lane&31, k = (lane>>5)*8 + e
//   C/D: col = lane&31, row = (reg&3) + 8*(reg>>2) + 4*(lane>>5)
// ---------------------------------------------------------------------------
__global__ __launch_bounds__(256) void attn_kernel(
    const unsigned short* __restrict__ qbuf, const unsigned short* __restrict__ kbuf,
    const unsigned short* __restrict__ vtbuf, unsigned short* __restrict__ obuf)
{
    __shared__ __align__(16) unsigned short sK[3][64 * 64];  // [kv][d], swizzled
    __shared__ __align__(16) unsigned short sV[3][64 * 64];  // [d][kv], swizzled

    const int tid  = threadIdx.x;
    const int wid  = tid >> 6;
    const int lane = tid & 63;
    const int hi   = lane >> 5;          // 0/1: which half-row of the q pair
    const int q5   = lane & 31;          // q column within wave tile

    const int x  = blockIdx.x;           // [0,512)
    const int p  = x >> 1, e = x & 1;    // pair id, heavy/light
    const int bh = p >> 3;               // 0..31; both pair members same bh
    const int j  = p & 7;
    const int s  = e ? j : (15 - j);     // pair work: (2(15-j)+2)+(2j+2)=34
    const int b  = bh >> 4, h = bh & 15;

    const unsigned short* Qh = qbuf  + (size_t)bh * S_LEN * HDIM;
    const unsigned short* Kh = kbuf  + (size_t)bh * S_LEN * HDIM;
    const unsigned short* Vt = vtbuf + (size_t)bh * HDIM * S_LEN;

    const int diag  = 2 * s + (wid >> 1);   // this wave's diagonal kv tile
    const int T     = 2 * s + 2;            // kv tiles staged by the block
    const int qrow0 = 128 * s + 32 * wid;
    const int qg    = qrow0 + q5;           // this lane-pair's q row

    // co-stage K tile (waves 0,1) + V^T tile (waves 2,3); 4 chunks/lane.
    // Pre-swizzled global source, linear LDS dest (rule #21).
    auto stage = [&](int t, int buf) {
#pragma unroll
        for (int i = 0; i < 4; ++i) {
            if (wid < 2) {
                int cidx = wid * 256 + i * 64 + lane;
                int row = cidx >> 3, col = ((cidx & 7) ^ (row & 7)) << 3;
                load_lds16(Kh + (size_t)(t * 64 + row) * HDIM + col,
                           &sK[buf][(wid * 256 + i * 64) * 8]);
            } else {
                int cidx = (wid - 2) * 256 + i * 64 + lane;
                int row = cidx >> 3, col = ((cidx & 7) ^ (row & 7)) << 3;
                load_lds16(Vt + (size_t)row * S_LEN + t * 64 + col,
                           &sV[buf][((wid - 2) * 256 + i * 64) * 8]);
            }
        }
    };

    // Q B-fragments (pre-scaled by 0.125*log2e): col=q5, k=ks*16+hi*8+e
    bf16x8 aq[4];
#pragma unroll
    for (int ks = 0; ks < 4; ++ks)
        aq[ks] = *(const bf16x8*)&Qh[(size_t)qg * HDIM + ks * 16 + hi * 8];

    f32x16 o2[2] = {};               // O[d=32*t2+(r&3)+4hi+8(r>>2)][q]
    float m_i = -1e30f, l_i = 0.f;   // per-lane partial l (pair-combined at end)

    stage(0, 0);
    stage(1, 1);

    for (int t = 0; t < T; ++t) {
        const int buf = t % 3;
        // counted wait: tile t landed (own 4 loads), t+1 still in flight
        asm volatile("s_waitcnt vmcnt(4)" ::: "memory");
        __builtin_amdgcn_s_barrier();
        stage(t + 2 < T ? t + 2 : t, (t + 2) % 3);   // clamp -> distinct buf

        if (t <= diag) {
            // swapped QK^T: acc[t2] = D[kv = t2*32 + rowfmt(r,hi)][q = q5]
            f32x16 acc[2] = {};
            __builtin_amdgcn_s_setprio(1);
#pragma unroll
            for (int ks = 0; ks < 4; ++ks) {
                bf16x8 k0 = *(const bf16x8*)&sK[buf][swz(q5,      ks * 16 + hi * 8)];
                bf16x8 k1 = *(const bf16x8*)&sK[buf][swz(q5 + 32, ks * 16 + hi * 8)];
                acc[0] = __builtin_amdgcn_mfma_f32_32x32x16_bf16(k0, aq[ks], acc[0], 0, 0, 0);
                acc[1] = __builtin_amdgcn_mfma_f32_32x32x16_bf16(k1, aq[ks], acc[1], 0, 0, 0);
            }
            __builtin_amdgcn_s_setprio(0);

            // causal mask (diagonal tile only): kv = t*64+t2*32+(r&3)+4hi+8(r>>2)
            if (t == diag) {
#pragma unroll
                for (int t2 = 0; t2 < 2; ++t2) {
                    int base = t * 64 + t2 * 32 + 4 * hi;
#pragma unroll
                    for (int r = 0; r < 16; ++r)
                        if (base + (r & 3) + 8 * (r >> 2) > qg) acc[t2][r] = -1e30f;
                }
            }

            // in-lane max over 32 values (tree); cross-lane only in rare branch
            float mx[8];
#pragma unroll
            for (int i = 0; i < 8; ++i)
                mx[i] = fmaxf(fmaxf(acc[i >> 2][(i & 3) * 4 + 0], acc[i >> 2][(i & 3) * 4 + 1]),
                              fmaxf(acc[i >> 2][(i & 3) * 4 + 2], acc[i >> 2][(i & 3) * 4 + 3]));
            float pm = fmaxf(fmaxf(fmaxf(mx[0], mx[1]), fmaxf(mx[2], mx[3])),
                             fmaxf(fmaxf(mx[4], mx[5]), fmaxf(mx[6], mx[7])));

            // defer-rescale (T13): wave-uniform trigger keeps m_i pair-consistent
            if (__any(pm > m_i + 8.0f)) {
                float pmr   = fmaxf(pm, __shfl_xor(pm, 32, 64));
                float m_new = fmaxf(m_i, pmr);
                float fac, dm = m_i - m_new;
                asm("v_exp_f32 %0, %1" : "=v"(fac) : "v"(dm));   // exp2 domain
                l_i *= fac;
                m_i  = m_new;
#pragma unroll
                for (int t2 = 0; t2 < 2; ++t2)
#pragma unroll
                    for (int r = 0; r < 16; ++r) o2[t2][r] *= fac;
            }

            // P = exp2(S - m_i); pack bf16 pairs in-register; per-lane sum
            unsigned pd[2][8];
            float lsum = 0.f;
#pragma unroll
            for (int t2 = 0; t2 < 2; ++t2) {
                float ev[16];
#pragma unroll
                for (int r = 0; r < 16; ++r) {
                    float a = acc[t2][r] - m_i;
                    asm("v_exp_f32 %0, %1" : "=v"(ev[r]) : "v"(a));
                }
                float s4[4];
#pragma unroll
                for (int u = 0; u < 4; ++u) {
                    s4[u] = (ev[4 * u] + ev[4 * u + 1]) + (ev[4 * u + 2] + ev[4 * u + 3]);
                    pd[t2][2 * u]     = pkbf(ev[4 * u],     ev[4 * u + 1]);
                    pd[t2][2 * u + 1] = pkbf(ev[4 * u + 2], ev[4 * u + 3]);
                }
                lsum += (s4[0] + s4[1]) + (s4[2] + s4[3]);
            }
            l_i += lsum;

            // PV: B-frag P[kv=ks*16+hi*8+e][q] built via pair exchange:
            //  hi=0 frag = [pd0, pd1, sx(pd0), sx(pd1)]   (kv 0-7 of window)
            //  hi=1 frag = [sx(pd2), sx(pd3), pd2, pd3]   (kv 8-15 of window)
            __builtin_amdgcn_s_setprio(1);
#pragma unroll
            for (int ks = 0; ks < 4; ++ks) {
                const int t2 = ks >> 1, k1 = ks & 1;
                unsigned p0 = pd[t2][4 * k1 + 0], p1 = pd[t2][4 * k1 + 1];
                unsigned p2 = pd[t2][4 * k1 + 2], p3 = pd[t2][4 * k1 + 3];
                unsigned s0 = __shfl_xor(p0, 32, 64), s1 = __shfl_xor(p1, 32, 64);
                unsigned s2 = __shfl_xor(p2, 32, 64), s3 = __shfl_xor(p3, 32, 64);
                u32x4 fw;
                fw[0] = hi ? s2 : p0;
                fw[1] = hi ? s3 : p1;
                fw[2] = hi ? p2 : s0;
                fw[3] = hi ? p3 : s1;
                bf16x8 pf = __builtin_bit_cast(bf16x8, fw);
                bf16x8 v0 = *(const bf16x8*)&sV[buf][swz(q5,      ks * 16 + hi * 8)];
                bf16x8 v1 = *(const bf16x8*)&sV[buf][swz(q5 + 32, ks * 16 + hi * 8)];
                o2[0] = __builtin_amdgcn_mfma_f32_32x32x16_bf16(v0, pf, o2[0], 0, 0, 0);
                o2[1] = __builtin_amdgcn_mfma_f32_32x32x16_bf16(v1, pf, o2[1], 0, 0, 0);
            }
            __builtin_amdgcn_s_setprio(0);
        }
        // no trailing drain: next iteration's vmcnt(4)+barrier gates reuse
    }

    // drain in-flight clamped tail prefetches before endpgm (R5 lesson)
    asm volatile("s_waitcnt vmcnt(0)" ::: "memory");

    // epilogue: combine the hi-pair's l partials once; 8x 8B stores per lane
    float l_full = l_i + __shfl_xor(l_i, 32, 64);
    float rl = 1.0f / l_full;
    unsigned short* orow = &obuf[((size_t)(b * S_LEN + qg)) * EMBD + h * HDIM];
#pragma unroll
    for (int t2 = 0; t2 < 2; ++t2)
#pragma unroll
        for (int u = 0; u < 4; ++u) {
            uint2 pw;
            pw.x = pkbf(o2[t2][4 * u] * rl,     o2[t2][4 * u + 1] * rl);
            pw.y = pkbf(o2[t2][4 * u + 2] * rl, o2[t2][4 * u + 3] * rl);
            *(uint2*)&orow[t2 * 32 + 4 * hi + 8 * u] = pw;
        }
}

extern "C" void kernel_launch(void* const* d_in, const int* in_sizes, int n_in,
                              void* d_out, int out_size, void* d_ws, size_t ws_size,
                              hipStream_t stream) {
    const float* hidden = (const float*)d_in[0];  // [2,2048,1024]
    const float* w_attn = (const float*)d_in[1];  // [3072,1024]
    const float* b_attn = (const float*)d_in[2];  // [3072]
    const float* w_proj = (const float*)d_in[3];  // [1024,1024]
    const float* b_proj = (const float*)d_in[4];  // [1024]
    float* out = (float*)d_out;                   // [2,2048,1024] fp32

    unsigned short* Xbf  = (unsigned short*)d_ws;          // 4096*1024
    unsigned short* Wabf = Xbf  + (size_t)ROWS * EMBD;     // 3072*1024
    unsigned short* Wpbf = Wabf + (size_t)3 * EMBD * EMBD; // 1024*1024
    unsigned short* qb   = Wpbf + (size_t)EMBD * EMBD;     // [B,H,S,D] (q pre-scaled)
    unsigned short* kb   = qb + (size_t)BATCHN * NHEAD * S_LEN * HDIM;
    unsigned short* vtb  = kb + (size_t)BATCHN * NHEAD * S_LEN * HDIM; // [B,H,D,S]
    unsigned short* ob   = vtb + (size_t)BATCHN * NHEAD * S_LEN * HDIM; // [B,S,E]

    // fp32 -> bf16 converts (single launch; dsts contiguous in ws)
    const int n0   = ROWS * EMBD;
    const int n01  = n0 + 3 * EMBD * EMBD;
    const int ntot = n01 + EMBD * EMBD;
    cvt3_f32_bf16<<<2048, 256, 0, stream>>>(hidden, w_attn, w_proj, Xbf,
                                            n0, n01, ntot);

    // QKV projection: q (pre-scaled), k, V^T
    gemm_bt<1><<<dim3(ROWS / 128, 3 * EMBD / 128), 256, 0, stream>>>(
        Xbf, Wabf, b_attn, nullptr, qb, kb, vtb, ROWS, 3 * EMBD, EMBD);

    // causal attention: adjacent-block complementary pairing (co-residency)
    attn_kernel<<<dim3(512), 256, 0, stream>>>(qb, kb, vtb, ob);

    // output projection -> fp32 out
    gemm_bt<0><<<dim3(ROWS / 128, EMBD / 128), 256, 0, stream>>>(
        ob, Wpbf, b_proj, out, nullptr, nullptr, nullptr, ROWS, EMBD, EMBD);
}

// Round 12
// 112.464 us; speedup vs baseline: 1.2037x; 1.2037x over previous
//
#include <hip/hip_runtime.h>
#include <stdint.h>

// Problem constants (GPT-2 attention block)
#define S_LEN  2048
#define EMBD   1024
#define NHEAD  16
#define HDIM   64
#define BATCHN 2
#define ROWS   (BATCHN * S_LEN)   // 4096 = flattened B*S

using bf16x8 = __attribute__((ext_vector_type(8))) __bf16;
using f32x4  = __attribute__((ext_vector_type(4))) float;
using f32x16 = __attribute__((ext_vector_type(16))) float;
using u32x4  = __attribute__((ext_vector_type(4))) unsigned;

typedef const __attribute__((address_space(1))) void* gas_ptr;
typedef __attribute__((address_space(3)))       void* las_ptr;

// Async global->LDS, 16B per lane. LDS dest = wave-uniform base + lane*16.
__device__ __forceinline__ void load_lds16(const void* g, void* l) {
    __builtin_amdgcn_global_load_lds((gas_ptr)(uintptr_t)g, (las_ptr)(uintptr_t)l, 16, 0, 0);
}

// fp32 -> bf16 round-to-nearest-even
__device__ __forceinline__ unsigned short f2bf(float f) {
    unsigned u = __builtin_bit_cast(unsigned, f);
    u += 0x7fffu + ((u >> 16) & 1u);
    return (unsigned short)(u >> 16);
}

// pack 2 floats -> 1 dword of 2 bf16 (lo = a, hi = b); hw cvt_pk (no builtin)
__device__ __forceinline__ unsigned pkbf(float a, float b) {
    unsigned r;
    asm("v_cvt_pk_bf16_f32 %0, %1, %2" : "=v"(r) : "v"(a), "v"(b));
    return r;
}

// XOR-swizzled element offset within a [R][64] bf16 tile (16B-chunk XOR row&7).
// Fixes the 16-way ds_read_b128 bank conflict of 128B-stride rows (T2).
__device__ __forceinline__ int swz(int row, int ebase) {
    int byte = (row << 7) + (ebase << 1);
    byte ^= (row & 7) << 4;
    return byte >> 1;
}

// Merged fp32->bf16 convert for 3 sources; destinations are contiguous in ws.
__global__ void cvt3_f32_bf16(const float* __restrict__ s0,
                              const float* __restrict__ s1,
                              const float* __restrict__ s2,
                              unsigned short* __restrict__ d,
                              int n0, int n01, int ntot) {
    int i = blockIdx.x * blockDim.x + threadIdx.x;
    int stride = gridDim.x * blockDim.x;
    for (int idx = i * 4; idx < ntot; idx += stride * 4) {
        const float* s; int off;
        if (idx < n0)       { s = s0; off = idx; }
        else if (idx < n01) { s = s1; off = idx - n0; }
        else                { s = s2; off = idx - n01; }
        float4 f = *(const float4*)(s + off);
        uint2 p;
        p.x = (unsigned)f2bf(f.x) | ((unsigned)f2bf(f.y) << 16);
        p.y = (unsigned)f2bf(f.z) | ((unsigned)f2bf(f.w) << 16);
        *(uint2*)(d + idx) = p;
    }
}

// ---------------------------------------------------------------------------
// bf16 GEMM, C[m][n] = sum_k A[m][k]*B[n][k] (+bias[n]).  A:[M][K] B:[N][K]
// 128x128 tile, BK=64, 4 waves (2x2), each wave 64x64 via 16x16x32 MFMA.
// LDS tiles XOR-swizzled (T2): pre-swizzled global source + swz() reads.
// MODE 0: write fp32 C[m*N+n] (+bias)                 (output projection)
// MODE 1: scatter bf16 q(pre-scaled)/k [B,H,S,D], V^T [B,H,D,S]  (QKV)
// ---------------------------------------------------------------------------
#define SCALE_Q 0.18033688011112042f   // 0.125 * log2(e): softmax in exp2 domain

template <int MODE>
__global__ __launch_bounds__(256) void gemm_bt(
    const unsigned short* __restrict__ A, const unsigned short* __restrict__ B,
    const float* __restrict__ bias, float* __restrict__ Cout,
    unsigned short* __restrict__ qb, unsigned short* __restrict__ kb,
    unsigned short* __restrict__ vb, int M, int N, int K)
{
    __shared__ __align__(16) unsigned short sA[128 * 64];
    __shared__ __align__(16) unsigned short sB[128 * 64];

    const int tid  = threadIdx.x;
    const int wid  = tid >> 6;
    const int lane = tid & 63;
    const int g    = lane >> 4;       // 0..3
    const int c    = lane & 15;       // 0..15
    const int bm   = blockIdx.x * 128;
    const int bn   = blockIdx.y * 128;
    const int wm   = (wid >> 1) * 64;
    const int wn   = (wid & 1) * 64;

    f32x4 acc[4][4] = {};

    for (int k0 = 0; k0 < K; k0 += 64) {
        // stage: pre-swizzled global source, linear LDS dest (rule #21)
#pragma unroll
        for (int i = 0; i < 4; ++i) {
            int cidx = i * 256 + tid;            // 16B chunk index in tile
            int row  = cidx >> 3;
            int col  = ((cidx & 7) ^ (row & 7)) << 3;
            load_lds16(A + (size_t)(bm + row) * K + k0 + col,
                       &sA[i * 2048 + wid * 512]);
            load_lds16(B + (size_t)(bn + row) * K + k0 + col,
                       &sB[i * 2048 + wid * 512]);
        }
        __syncthreads();
#pragma unroll
        for (int kk = 0; kk < 2; ++kk) {
            bf16x8 af[4], bfr[4];
#pragma unroll
            for (int i = 0; i < 4; ++i)
                af[i] = *(const bf16x8*)&sA[swz(wm + i * 16 + c, kk * 32 + g * 8)];
#pragma unroll
            for (int j = 0; j < 4; ++j)
                bfr[j] = *(const bf16x8*)&sB[swz(wn + j * 16 + c, kk * 32 + g * 8)];
#pragma unroll
            for (int i = 0; i < 4; ++i)
#pragma unroll
                for (int j = 0; j < 4; ++j)
                    acc[i][j] = __builtin_amdgcn_mfma_f32_16x16x32_bf16(
                        af[i], bfr[j], acc[i][j], 0, 0, 0);
        }
        __syncthreads();
    }

#pragma unroll
    for (int i = 0; i < 4; ++i)
#pragma unroll
        for (int j = 0; j < 4; ++j) {
            int n = bn + wn + j * 16 + c;
            float bv = bias[n];
            if (MODE == 0) {
#pragma unroll
                for (int r = 0; r < 4; ++r) {
                    int m = bm + wm + i * 16 + g * 4 + r;
                    Cout[(size_t)m * N + n] = acc[i][j][r] + bv;
                }
            } else {
                int which = n >> 10, h = (n & 1023) >> 6, d = n & 63;
                if (which < 2) {
                    unsigned short* dst = (which == 0) ? qb : kb;
                    float sc = (which == 0) ? SCALE_Q : 1.0f;
#pragma unroll
                    for (int r = 0; r < 4; ++r) {
                        int m = bm + wm + i * 16 + g * 4 + r;
                        int b = m >> 11, s = m & 2047;
                        dst[(((size_t)b * NHEAD + h) * S_LEN + s) * HDIM + d] =
                            f2bf((acc[i][j][r] + bv) * sc);
                    }
                } else {
                    // V^T [B,H,D,S]: pack 4 consecutive s into one 8B store
                    int m0 = bm + wm + i * 16 + g * 4;
                    int b = m0 >> 11, s0 = m0 & 2047;
                    uint2 p;
                    p.x = pkbf(acc[i][j][0] + bv, acc[i][j][1] + bv);
                    p.y = pkbf(acc[i][j][2] + bv, acc[i][j][3] + bv);
                    *(uint2*)&vb[(((size_t)b * NHEAD + h) * HDIM + d) * S_LEN + s0] = p;
                }
            }
        }
}

// ---------------------------------------------------------------------------
// Flash-style causal attention — 32x32 MFMA, PAIR-IN-BLOCK (R11 post-mortem).
//
// DISPATCH MODEL (R9=R10 identical, R11 +22%, Occupancy ~12% = 4 waves/CU):
// only ONE block per CU is resident; the grid runs as sequential rounds and
// cross-block pairing never co-executes. So the complementary pair must live
// INSIDE one block: grid 256 x 512 threads (8 waves). j=x>>5, bh=x&31
// (XCD = bh%8: R11's bh=x>>4 spread heads over all XCDs -> FETCH 12->47MB).
// Waves 0-3 compute q-super 15-j, waves 4-7 compute q-super j, SHARING the
// staged K/V (light range is a subset). Wave i and i+4 share SIMD i -> every
// SIMD gets ~33 tile-computes uniformly; single round, no tail.
// Staging: 8 waves x 2 chunks each (waves 0-3: K, 4-7: V^T); vmcnt count
// is 2 per stage; 3-buffer, counted vmcnt(2), one barrier/tile.
// Swapped QK^T (D[kv][q=lane&31]); q-row owned by a hi-lane pair (lane^32).
// P stays in registers (cvt_pk + shfl_xor(32) + hi-selects).
// 32x32x16 layouts (m74/m101/m89-verified):
//   A/B: row|col = lane&31, k = (lane>>5)*8 + e
//   C/D: col = lane&31, row = (reg&3) + 8*(reg>>2) + 4*(lane>>5)
// ---------------------------------------------------------------------------
__global__ __launch_bounds__(512) void attn_kernel(
    const unsigned short* __restrict__ qbuf, const unsigned short* __restrict__ kbuf,
    const unsigned short* __restrict__ vtbuf, unsigned short* __restrict__ obuf)
{
    __shared__ __align__(16) unsigned short sK[3][64 * 64];  // [kv][d], swizzled
    __shared__ __align__(16) unsigned short sV[3][64 * 64];  // [d][kv], swizzled

    const int tid  = threadIdx.x;
    const int wid  = tid >> 6;           // 0..7
    const int wg   = wid & 3;            // wave-in-group
    const int grp  = wid >> 2;           // 0 = heavy super, 1 = light super
    const int lane = tid & 63;
    const int hi   = lane >> 5;          // 0/1: which half-row of the q pair
    const int q5   = lane & 31;          // q column within wave tile

    const int x  = blockIdx.x;           // [0,256)
    const int j  = x >> 5;               // 0..7
    const int bh = x & 31;               // XCD = bh%8 (L2 locality)
    const int b  = bh >> 4, h = bh & 15;

    const int s  = grp ? j : (15 - j);   // this wave-group's q-super
    const int T  = 2 * (15 - j) + 2;     // tiles staged (heavy's range)

    const unsigned short* Qh = qbuf  + (size_t)bh * S_LEN * HDIM;
    const unsigned short* Kh = kbuf  + (size_t)bh * S_LEN * HDIM;
    const unsigned short* Vt = vtbuf + (size_t)bh * HDIM * S_LEN;

    const int diag  = 2 * s + (wg >> 1);    // this wave's diagonal kv tile
    const int qrow0 = 128 * s + 32 * wg;
    const int qg    = qrow0 + q5;           // this lane-pair's q row

    // co-stage K (waves 0-3) + V^T (waves 4-7); 2 chunks/lane.
    // Pre-swizzled global source, linear LDS dest (rule #21).
    auto stage = [&](int t, int buf) {
#pragma unroll
        for (int i = 0; i < 2; ++i) {
            int cbase = wg * 128 + i * 64;         // wave-uniform chunk base
            int cidx  = cbase + lane;
            int row = cidx >> 3, col = ((cidx & 7) ^ (row & 7)) << 3;
            if (grp == 0)
                load_lds16(Kh + (size_t)(t * 64 + row) * HDIM + col,
                           &sK[buf][cbase * 8]);
            else
                load_lds16(Vt + (size_t)row * S_LEN + t * 64 + col,
                           &sV[buf][cbase * 8]);
        }
    };

    // Q B-fragments (pre-scaled by 0.125*log2e): col=q5, k=ks*16+hi*8+e
    bf16x8 aq[4];
#pragma unroll
    for (int ks = 0; ks < 4; ++ks)
        aq[ks] = *(const bf16x8*)&Qh[(size_t)qg * HDIM + ks * 16 + hi * 8];

    f32x16 o2[2] = {};               // O[d=32*t2+(r&3)+4hi+8(r>>2)][q]
    float m_i = -1e30f, l_i = 0.f;   // per-lane partial l (pair-combined at end)

    stage(0, 0);
    stage(1, 1);

    for (int t = 0; t < T; ++t) {
        const int buf = t % 3;
        // counted wait: own tile-t loads landed (2), tile t+1 still in flight
        asm volatile("s_waitcnt vmcnt(2)" ::: "memory");
        __builtin_amdgcn_s_barrier();
        stage(t + 2 < T ? t + 2 : t, (t + 2) % 3);   // clamp -> distinct buf

        if (t <= diag) {
            // swapped QK^T: acc[t2] = D[kv = t2*32 + rowfmt(r,hi)][q = q5]
            f32x16 acc[2] = {};
            __builtin_amdgcn_s_setprio(1);
#pragma unroll
            for (int ks = 0; ks < 4; ++ks) {
                bf16x8 k0 = *(const bf16x8*)&sK[buf][swz(q5,      ks * 16 + hi * 8)];
                bf16x8 k1 = *(const bf16x8*)&sK[buf][swz(q5 + 32, ks * 16 + hi * 8)];
                acc[0] = __builtin_amdgcn_mfma_f32_32x32x16_bf16(k0, aq[ks], acc[0], 0, 0, 0);
                acc[1] = __builtin_amdgcn_mfma_f32_32x32x16_bf16(k1, aq[ks], acc[1], 0, 0, 0);
            }
            __builtin_amdgcn_s_setprio(0);

            // causal mask (diagonal tile only): kv = t*64+t2*32+(r&3)+4hi+8(r>>2)
            if (t == diag) {
#pragma unroll
                for (int t2 = 0; t2 < 2; ++t2) {
                    int base = t * 64 + t2 * 32 + 4 * hi;
#pragma unroll
                    for (int r = 0; r < 16; ++r)
                        if (base + (r & 3) + 8 * (r >> 2) > qg) acc[t2][r] = -1e30f;
                }
            }

            // in-lane max over 32 values (tree); cross-lane only in rare branch
            float mx[8];
#pragma unroll
            for (int i = 0; i < 8; ++i)
                mx[i] = fmaxf(fmaxf(acc[i >> 2][(i & 3) * 4 + 0], acc[i >> 2][(i & 3) * 4 + 1]),
                              fmaxf(acc[i >> 2][(i & 3) * 4 + 2], acc[i >> 2][(i & 3) * 4 + 3]));
            float pm = fmaxf(fmaxf(fmaxf(mx[0], mx[1]), fmaxf(mx[2], mx[3])),
                             fmaxf(fmaxf(mx[4], mx[5]), fmaxf(mx[6], mx[7])));

            // defer-rescale (T13): wave-uniform trigger keeps m_i pair-consistent
            if (__any(pm > m_i + 8.0f)) {
                float pmr   = fmaxf(pm, __shfl_xor(pm, 32, 64));
                float m_new = fmaxf(m_i, pmr);
                float fac, dm = m_i - m_new;
                asm("v_exp_f32 %0, %1" : "=v"(fac) : "v"(dm));   // exp2 domain
                l_i *= fac;
                m_i  = m_new;
#pragma unroll
                for (int t2 = 0; t2 < 2; ++t2)
#pragma unroll
                    for (int r = 0; r < 16; ++r) o2[t2][r] *= fac;
            }

            // P = exp2(S - m_i); pack bf16 pairs in-register; per-lane sum
            unsigned pd[2][8];
            float lsum = 0.f;
#pragma unroll
            for (int t2 = 0; t2 < 2; ++t2) {
                float ev[16];
#pragma unroll
                for (int r = 0; r < 16; ++r) {
                    float a = acc[t2][r] - m_i;
                    asm("v_exp_f32 %0, %1" : "=v"(ev[r]) : "v"(a));
                }
                float s4[4];
#pragma unroll
                for (int u = 0; u < 4; ++u) {
                    s4[u] = (ev[4 * u] + ev[4 * u + 1]) + (ev[4 * u + 2] + ev[4 * u + 3]);
                    pd[t2][2 * u]     = pkbf(ev[4 * u],     ev[4 * u + 1]);
                    pd[t2][2 * u + 1] = pkbf(ev[4 * u + 2], ev[4 * u + 3]);
                }
                lsum += (s4[0] + s4[1]) + (s4[2] + s4[3]);
            }
            l_i += lsum;

            // PV: B-frag P[kv=ks*16+hi*8+e][q] built via pair exchange:
            //  hi=0 frag = [pd0, pd1, sx(pd0), sx(pd1)]   (kv 0-7 of window)
            //  hi=1 frag = [sx(pd2), sx(pd3), pd2, pd3]   (kv 8-15 of window)
            __builtin_amdgcn_s_setprio(1);
#pragma unroll
            for (int ks = 0; ks < 4; ++ks) {
                const int t2 = ks >> 1, k1 = ks & 1;
                unsigned p0 = pd[t2][4 * k1 + 0], p1 = pd[t2][4 * k1 + 1];
                unsigned p2 = pd[t2][4 * k1 + 2], p3 = pd[t2][4 * k1 + 3];
                unsigned s0 = __shfl_xor(p0, 32, 64), s1 = __shfl_xor(p1, 32, 64);
                unsigned s2 = __shfl_xor(p2, 32, 64), s3 = __shfl_xor(p3, 32, 64);
                u32x4 fw;
                fw[0] = hi ? s2 : p0;
                fw[1] = hi ? s3 : p1;
                fw[2] = hi ? p2 : s0;
                fw[3] = hi ? p3 : s1;
                bf16x8 pf = __builtin_bit_cast(bf16x8, fw);
                bf16x8 v0 = *(const bf16x8*)&sV[buf][swz(q5,      ks * 16 + hi * 8)];
                bf16x8 v1 = *(const bf16x8*)&sV[buf][swz(q5 + 32, ks * 16 + hi * 8)];
                o2[0] = __builtin_amdgcn_mfma_f32_32x32x16_bf16(v0, pf, o2[0], 0, 0, 0);
                o2[1] = __builtin_amdgcn_mfma_f32_32x32x16_bf16(v1, pf, o2[1], 0, 0, 0);
            }
            __builtin_amdgcn_s_setprio(0);
        }
        // no trailing drain: next iteration's vmcnt(2)+barrier gates reuse
    }

    // drain in-flight clamped tail prefetches before endpgm (R5 lesson)
    asm volatile("s_waitcnt vmcnt(0)" ::: "memory");

    // epilogue: combine the hi-pair's l partials once; 8x 8B stores per lane
    float l_full = l_i + __shfl_xor(l_i, 32, 64);
    float rl = 1.0f / l_full;
    unsigned short* orow = &obuf[((size_t)(b * S_LEN + qg)) * EMBD + h * HDIM];
#pragma unroll
    for (int t2 = 0; t2 < 2; ++t2)
#pragma unroll
        for (int u = 0; u < 4; ++u) {
            uint2 pw;
            pw.x = pkbf(o2[t2][4 * u] * rl,     o2[t2][4 * u + 1] * rl);
            pw.y = pkbf(o2[t2][4 * u + 2] * rl, o2[t2][4 * u + 3] * rl);
            *(uint2*)&orow[t2 * 32 + 4 * hi + 8 * u] = pw;
        }
}

extern "C" void kernel_launch(void* const* d_in, const int* in_sizes, int n_in,
                              void* d_out, int out_size, void* d_ws, size_t ws_size,
                              hipStream_t stream) {
    const float* hidden = (const float*)d_in[0];  // [2,2048,1024]
    const float* w_attn = (const float*)d_in[1];  // [3072,1024]
    const float* b_attn = (const float*)d_in[2];  // [3072]
    const float* w_proj = (const float*)d_in[3];  // [1024,1024]
    const float* b_proj = (const float*)d_in[4];  // [1024]
    float* out = (float*)d_out;                   // [2,2048,1024] fp32

    unsigned short* Xbf  = (unsigned short*)d_ws;          // 4096*1024
    unsigned short* Wabf = Xbf  + (size_t)ROWS * EMBD;     // 3072*1024
    unsigned short* Wpbf = Wabf + (size_t)3 * EMBD * EMBD; // 1024*1024
    unsigned short* qb   = Wpbf + (size_t)EMBD * EMBD;     // [B,H,S,D] (q pre-scaled)
    unsigned short* kb   = qb + (size_t)BATCHN * NHEAD * S_LEN * HDIM;
    unsigned short* vtb  = kb + (size_t)BATCHN * NHEAD * S_LEN * HDIM; // [B,H,D,S]
    unsigned short* ob   = vtb + (size_t)BATCHN * NHEAD * S_LEN * HDIM; // [B,S,E]

    // fp32 -> bf16 converts (single launch; dsts contiguous in ws)
    const int n0   = ROWS * EMBD;
    const int n01  = n0 + 3 * EMBD * EMBD;
    const int ntot = n01 + EMBD * EMBD;
    cvt3_f32_bf16<<<2048, 256, 0, stream>>>(hidden, w_attn, w_proj, Xbf,
                                            n0, n01, ntot);

    // QKV projection: q (pre-scaled), k, V^T
    gemm_bt<1><<<dim3(ROWS / 128, 3 * EMBD / 128), 256, 0, stream>>>(
        Xbf, Wabf, b_attn, nullptr, qb, kb, vtb, ROWS, 3 * EMBD, EMBD);

    // causal attention: 256 blocks x 8 waves, pair-in-block, shared staging
    attn_kernel<<<dim3(256), 512, 0, stream>>>(qb, kb, vtb, ob);

    // output projection -> fp32 out
    gemm_bt<0><<<dim3(ROWS / 128, EMBD / 128), 256, 0, stream>>>(
        ob, Wpbf, b_proj, out, nullptr, nullptr, nullptr, ROWS, EMBD, EMBD);
}

// Round 13
// 112.035 us; speedup vs baseline: 1.2083x; 1.0038x over previous
//
#include <hip/hip_runtime.h>
#include <stdint.h>

// Problem constants (GPT-2 attention block)
#define S_LEN  2048
#define EMBD   1024
#define NHEAD  16
#define HDIM   64
#define BATCHN 2
#define ROWS   (BATCHN * S_LEN)   // 4096 = flattened B*S

using bf16x8 = __attribute__((ext_vector_type(8))) __bf16;
using f32x4  = __attribute__((ext_vector_type(4))) float;
using f32x16 = __attribute__((ext_vector_type(16))) float;
using u32x4  = __attribute__((ext_vector_type(4))) unsigned;

typedef const __attribute__((address_space(1))) void* gas_ptr;
typedef __attribute__((address_space(3)))       void* las_ptr;

// Async global->LDS, 16B per lane. LDS dest = wave-uniform base + lane*16.
__device__ __forceinline__ void load_lds16(const void* g, void* l) {
    __builtin_amdgcn_global_load_lds((gas_ptr)(uintptr_t)g, (las_ptr)(uintptr_t)l, 16, 0, 0);
}

// fp32 -> bf16 round-to-nearest-even
__device__ __forceinline__ unsigned short f2bf(float f) {
    unsigned u = __builtin_bit_cast(unsigned, f);
    u += 0x7fffu + ((u >> 16) & 1u);
    return (unsigned short)(u >> 16);
}

// pack 2 floats -> 1 dword of 2 bf16 (lo = a, hi = b); hw cvt_pk (no builtin)
__device__ __forceinline__ unsigned pkbf(float a, float b) {
    unsigned r;
    asm("v_cvt_pk_bf16_f32 %0, %1, %2" : "=v"(r) : "v"(a), "v"(b));
    return r;
}

// XOR-swizzled element offset within a [R][64] bf16 tile (128B rows, 8 chunks:
// chunk ^= row&7). Fixes 16-way ds_read_b128 conflicts on 128B-stride rows.
__device__ __forceinline__ int swz(int row, int ebase) {
    int byte = (row << 7) + (ebase << 1);
    byte ^= (row & 7) << 4;
    return byte >> 1;
}

// Same for [R][128] bf16 tiles (256B rows, 16 chunks: chunk ^= row&15).
__device__ __forceinline__ int swzV(int row, int ebase) {
    int byte = (row << 8) + (ebase << 1);
    byte ^= (row & 15) << 4;
    return byte >> 1;
}

// Merged fp32->bf16 convert for 3 sources; destinations are contiguous in ws.
__global__ void cvt3_f32_bf16(const float* __restrict__ s0,
                              const float* __restrict__ s1,
                              const float* __restrict__ s2,
                              unsigned short* __restrict__ d,
                              int n0, int n01, int ntot) {
    int i = blockIdx.x * blockDim.x + threadIdx.x;
    int stride = gridDim.x * blockDim.x;
    for (int idx = i * 4; idx < ntot; idx += stride * 4) {
        const float* s; int off;
        if (idx < n0)       { s = s0; off = idx; }
        else if (idx < n01) { s = s1; off = idx - n0; }
        else                { s = s2; off = idx - n01; }
        float4 f = *(const float4*)(s + off);
        uint2 p;
        p.x = (unsigned)f2bf(f.x) | ((unsigned)f2bf(f.y) << 16);
        p.y = (unsigned)f2bf(f.z) | ((unsigned)f2bf(f.w) << 16);
        *(uint2*)(d + idx) = p;
    }
}

// ---------------------------------------------------------------------------
// bf16 GEMM, C[m][n] = sum_k A[m][k]*B[n][k] (+bias[n]).  A:[M][K] B:[N][K]
// 128x128 tile, BK=64, 4 waves (2x2), each wave 64x64 via 16x16x32 MFMA.
// LDS tiles XOR-swizzled (T2): pre-swizzled global source + swz() reads.
// MODE 0: write fp32 C[m*N+n] (+bias)                 (output projection)
// MODE 1: scatter bf16 q(pre-scaled)/k [B,H,S,D], V^T [B,H,D,S]  (QKV)
// ---------------------------------------------------------------------------
#define SCALE_Q 0.18033688011112042f   // 0.125 * log2(e): softmax in exp2 domain

template <int MODE>
__global__ __launch_bounds__(256) void gemm_bt(
    const unsigned short* __restrict__ A, const unsigned short* __restrict__ B,
    const float* __restrict__ bias, float* __restrict__ Cout,
    unsigned short* __restrict__ qb, unsigned short* __restrict__ kb,
    unsigned short* __restrict__ vb, int M, int N, int K)
{
    __shared__ __align__(16) unsigned short sA[128 * 64];
    __shared__ __align__(16) unsigned short sB[128 * 64];

    const int tid  = threadIdx.x;
    const int wid  = tid >> 6;
    const int lane = tid & 63;
    const int g    = lane >> 4;       // 0..3
    const int c    = lane & 15;       // 0..15
    const int bm   = blockIdx.x * 128;
    const int bn   = blockIdx.y * 128;
    const int wm   = (wid >> 1) * 64;
    const int wn   = (wid & 1) * 64;

    f32x4 acc[4][4] = {};

    for (int k0 = 0; k0 < K; k0 += 64) {
        // stage: pre-swizzled global source, linear LDS dest (rule #21)
#pragma unroll
        for (int i = 0; i < 4; ++i) {
            int cidx = i * 256 + tid;            // 16B chunk index in tile
            int row  = cidx >> 3;
            int col  = ((cidx & 7) ^ (row & 7)) << 3;
            load_lds16(A + (size_t)(bm + row) * K + k0 + col,
                       &sA[i * 2048 + wid * 512]);
            load_lds16(B + (size_t)(bn + row) * K + k0 + col,
                       &sB[i * 2048 + wid * 512]);
        }
        __syncthreads();
#pragma unroll
        for (int kk = 0; kk < 2; ++kk) {
            bf16x8 af[4], bfr[4];
#pragma unroll
            for (int i = 0; i < 4; ++i)
                af[i] = *(const bf16x8*)&sA[swz(wm + i * 16 + c, kk * 32 + g * 8)];
#pragma unroll
            for (int j = 0; j < 4; ++j)
                bfr[j] = *(const bf16x8*)&sB[swz(wn + j * 16 + c, kk * 32 + g * 8)];
#pragma unroll
            for (int i = 0; i < 4; ++i)
#pragma unroll
                for (int j = 0; j < 4; ++j)
                    acc[i][j] = __builtin_amdgcn_mfma_f32_16x16x32_bf16(
                        af[i], bfr[j], acc[i][j], 0, 0, 0);
        }
        __syncthreads();
    }

#pragma unroll
    for (int i = 0; i < 4; ++i)
#pragma unroll
        for (int j = 0; j < 4; ++j) {
            int n = bn + wn + j * 16 + c;
            float bv = bias[n];
            if (MODE == 0) {
#pragma unroll
                for (int r = 0; r < 4; ++r) {
                    int m = bm + wm + i * 16 + g * 4 + r;
                    Cout[(size_t)m * N + n] = acc[i][j][r] + bv;
                }
            } else {
                int which = n >> 10, h = (n & 1023) >> 6, d = n & 63;
                if (which < 2) {
                    unsigned short* dst = (which == 0) ? qb : kb;
                    float sc = (which == 0) ? SCALE_Q : 1.0f;
#pragma unroll
                    for (int r = 0; r < 4; ++r) {
                        int m = bm + wm + i * 16 + g * 4 + r;
                        int b = m >> 11, s = m & 2047;
                        dst[(((size_t)b * NHEAD + h) * S_LEN + s) * HDIM + d] =
                            f2bf((acc[i][j][r] + bv) * sc);
                    }
                } else {
                    // V^T [B,H,D,S]: pack 4 consecutive s into one 8B store
                    int m0 = bm + wm + i * 16 + g * 4;
                    int b = m0 >> 11, s0 = m0 & 2047;
                    uint2 p;
                    p.x = pkbf(acc[i][j][0] + bv, acc[i][j][1] + bv);
                    p.y = pkbf(acc[i][j][2] + bv, acc[i][j][3] + bv);
                    *(uint2*)&vb[(((size_t)b * NHEAD + h) * HDIM + d) * S_LEN + s0] = p;
                }
            }
        }
}

// ---------------------------------------------------------------------------
// Flash-style causal attention — 32x32 MFMA, pair-in-block, KVBLK=128.
//
// R12 confirmed: 1 block/CU resident; pair-in-block (heavy super 15-j on
// waves 0-3, light super j on waves 4-7, shared K/V staging) balances every
// SIMD at ~17 128-tile computes. R13: halve the per-kv SYNC overhead by
// staging 128-wide KV tiles (one vmcnt+barrier per 128 kv instead of 64)
// and running the proven 64-kv compute body twice per staged tile.
// K [128][64] swz (8-chunk rows); V^T [64][128] swzV (16-chunk rows);
// 3 buffers (96KB), counted vmcnt(4) (4 chunks/wave/stage), 1 barrier/tile.
// Swapped QK^T (D[kv][q=lane&31]); q-row owned by hi-lane pair (lane^32);
// P in registers (cvt_pk + shfl_xor(32) + hi-selects); defer-rescale THR=8.
// 32x32x16 layouts (m74/m101/m89-verified):
//   A/B: row|col = lane&31, k = (lane>>5)*8 + e
//   C/D: col = lane&31, row = (reg&3) + 8*(reg>>2) + 4*(lane>>5)
// ---------------------------------------------------------------------------
__global__ __launch_bounds__(512) void attn_kernel(
    const unsigned short* __restrict__ qbuf, const unsigned short* __restrict__ kbuf,
    const unsigned short* __restrict__ vtbuf, unsigned short* __restrict__ obuf)
{
    __shared__ __align__(16) unsigned short sK[3][128 * 64];  // [kv][d], swz
    __shared__ __align__(16) unsigned short sV[3][64 * 128];  // [d][kv], swzV

    const int tid  = threadIdx.x;
    const int wid  = tid >> 6;           // 0..7
    const int wg   = wid & 3;            // wave-in-group
    const int grp  = wid >> 2;           // 0 = heavy super (+K stage), 1 = light (+V stage)
    const int lane = tid & 63;
    const int hi   = lane >> 5;          // 0/1: which half-row of the q pair
    const int q5   = lane & 31;          // q column within wave tile

    const int x  = blockIdx.x;           // [0,256)
    const int j  = x >> 5;               // 0..7
    const int bh = x & 31;               // XCD = bh%8 (L2 locality)
    const int b  = bh >> 4, h = bh & 15;

    const int s  = grp ? j : (15 - j);   // this wave-group's q-super
    const int TT = 16 - j;               // 128-tiles staged (heavy's range)

    const unsigned short* Qh = qbuf  + (size_t)bh * S_LEN * HDIM;
    const unsigned short* Kh = kbuf  + (size_t)bh * S_LEN * HDIM;
    const unsigned short* Vt = vtbuf + (size_t)bh * HDIM * S_LEN;

    const int diag64 = 2 * s + (wg >> 1);   // this wave's diagonal 64-tile
    const int qrow0  = 128 * s + 32 * wg;
    const int qg     = qrow0 + q5;          // this lane-pair's q row

    // stage one 128-wide KV tile: waves 0-3 K (16KB), waves 4-7 V^T (16KB);
    // 4 chunks/lane. Pre-swizzled global source, linear LDS dest (rule #21).
    auto stage = [&](int t, int buf) {
#pragma unroll
        for (int i = 0; i < 4; ++i) {
            int cbase = wg * 256 + i * 64;       // wave-uniform chunk base
            int cidx  = cbase + lane;
            if (grp == 0) {                      // K: 128 rows x 128B (8 chunks)
                int row = cidx >> 3, col = ((cidx & 7) ^ (row & 7)) << 3;
                load_lds16(Kh + (size_t)(t * 128 + row) * HDIM + col,
                           &sK[buf][cbase * 8]);
            } else {                             // V^T: 64 rows x 256B (16 chunks)
                int row = cidx >> 4, col = ((cidx & 15) ^ (row & 15)) << 3;
                load_lds16(Vt + (size_t)row * S_LEN + t * 128 + col,
                           &sV[buf][cbase * 8]);
            }
        }
    };

    // Q B-fragments (pre-scaled by 0.125*log2e): col=q5, k=ks*16+hi*8+e
    bf16x8 aq[4];
#pragma unroll
    for (int ks = 0; ks < 4; ++ks)
        aq[ks] = *(const bf16x8*)&Qh[(size_t)qg * HDIM + ks * 16 + hi * 8];

    f32x16 o2[2] = {};               // O[d=32*t2+(r&3)+4hi+8(r>>2)][q]
    float m_i = -1e30f, l_i = 0.f;   // per-lane partial l (pair-combined at end)

    stage(0, 0);
    stage(1, 1);

    for (int tt = 0; tt < TT; ++tt) {
        const int buf = tt % 3;
        // counted wait: own tile-tt loads landed (4), tile tt+1 still in flight
        asm volatile("s_waitcnt vmcnt(4)" ::: "memory");
        __builtin_amdgcn_s_barrier();
        stage(tt + 2 < TT ? tt + 2 : TT - 1, (tt + 2) % 3);  // clamp: distinct buf

#pragma unroll
        for (int half = 0; half < 2; ++half) {
            const int t64 = 2 * tt + half;
            if (t64 > diag64) break;

            // swapped QK^T: acc[t2] = D[kv = t2*32 + rowfmt(r,hi)][q = q5]
            f32x16 acc[2] = {};
            __builtin_amdgcn_s_setprio(1);
#pragma unroll
            for (int ks = 0; ks < 4; ++ks) {
                bf16x8 k0 = *(const bf16x8*)&sK[buf][swz(half * 64 + q5,      ks * 16 + hi * 8)];
                bf16x8 k1 = *(const bf16x8*)&sK[buf][swz(half * 64 + q5 + 32, ks * 16 + hi * 8)];
                acc[0] = __builtin_amdgcn_mfma_f32_32x32x16_bf16(k0, aq[ks], acc[0], 0, 0, 0);
                acc[1] = __builtin_amdgcn_mfma_f32_32x32x16_bf16(k1, aq[ks], acc[1], 0, 0, 0);
            }
            __builtin_amdgcn_s_setprio(0);

            // causal mask (diagonal 64-tile only)
            if (t64 == diag64) {
#pragma unroll
                for (int t2 = 0; t2 < 2; ++t2) {
                    int base = t64 * 64 + t2 * 32 + 4 * hi;
#pragma unroll
                    for (int r = 0; r < 16; ++r)
                        if (base + (r & 3) + 8 * (r >> 2) > qg) acc[t2][r] = -1e30f;
                }
            }

            // in-lane max over 32 values (tree); cross-lane only in rare branch
            float mx[8];
#pragma unroll
            for (int i = 0; i < 8; ++i)
                mx[i] = fmaxf(fmaxf(acc[i >> 2][(i & 3) * 4 + 0], acc[i >> 2][(i & 3) * 4 + 1]),
                              fmaxf(acc[i >> 2][(i & 3) * 4 + 2], acc[i >> 2][(i & 3) * 4 + 3]));
            float pm = fmaxf(fmaxf(fmaxf(mx[0], mx[1]), fmaxf(mx[2], mx[3])),
                             fmaxf(fmaxf(mx[4], mx[5]), fmaxf(mx[6], mx[7])));

            // defer-rescale (T13): wave-uniform trigger keeps m_i pair-consistent
            if (__any(pm > m_i + 8.0f)) {
                float pmr   = fmaxf(pm, __shfl_xor(pm, 32, 64));
                float m_new = fmaxf(m_i, pmr);
                float fac, dm = m_i - m_new;
                asm("v_exp_f32 %0, %1" : "=v"(fac) : "v"(dm));   // exp2 domain
                l_i *= fac;
                m_i  = m_new;
#pragma unroll
                for (int t2 = 0; t2 < 2; ++t2)
#pragma unroll
                    for (int r = 0; r < 16; ++r) o2[t2][r] *= fac;
            }

            // P = exp2(S - m_i); pack bf16 pairs in-register; per-lane sum
            unsigned pd[2][8];
            float lsum = 0.f;
#pragma unroll
            for (int t2 = 0; t2 < 2; ++t2) {
                float ev[16];
#pragma unroll
                for (int r = 0; r < 16; ++r) {
                    float a = acc[t2][r] - m_i;
                    asm("v_exp_f32 %0, %1" : "=v"(ev[r]) : "v"(a));
                }
                float s4[4];
#pragma unroll
                for (int u = 0; u < 4; ++u) {
                    s4[u] = (ev[4 * u] + ev[4 * u + 1]) + (ev[4 * u + 2] + ev[4 * u + 3]);
                    pd[t2][2 * u]     = pkbf(ev[4 * u],     ev[4 * u + 1]);
                    pd[t2][2 * u + 1] = pkbf(ev[4 * u + 2], ev[4 * u + 3]);
                }
                lsum += (s4[0] + s4[1]) + (s4[2] + s4[3]);
            }
            l_i += lsum;

            // PV: B-frag P[kv=ks*16+hi*8+e][q] built via pair exchange:
            //  hi=0 frag = [pd0, pd1, sx(pd0), sx(pd1)]   (kv 0-7 of window)
            //  hi=1 frag = [sx(pd2), sx(pd3), pd2, pd3]   (kv 8-15 of window)
            __builtin_amdgcn_s_setprio(1);
#pragma unroll
            for (int ks = 0; ks < 4; ++ks) {
                const int t2 = ks >> 1, k1 = ks & 1;
                unsigned p0 = pd[t2][4 * k1 + 0], p1 = pd[t2][4 * k1 + 1];
                unsigned p2 = pd[t2][4 * k1 + 2], p3 = pd[t2][4 * k1 + 3];
                unsigned s0 = __shfl_xor(p0, 32, 64), s1 = __shfl_xor(p1, 32, 64);
                unsigned s2 = __shfl_xor(p2, 32, 64), s3 = __shfl_xor(p3, 32, 64);
                u32x4 fw;
                fw[0] = hi ? s2 : p0;
                fw[1] = hi ? s3 : p1;
                fw[2] = hi ? p2 : s0;
                fw[3] = hi ? p3 : s1;
                bf16x8 pf = __builtin_bit_cast(bf16x8, fw);
                bf16x8 v0 = *(const bf16x8*)&sV[buf][swzV(q5,      half * 64 + ks * 16 + hi * 8)];
                bf16x8 v1 = *(const bf16x8*)&sV[buf][swzV(q5 + 32, half * 64 + ks * 16 + hi * 8)];
                o2[0] = __builtin_amdgcn_mfma_f32_32x32x16_bf16(v0, pf, o2[0], 0, 0, 0);
                o2[1] = __builtin_amdgcn_mfma_f32_32x32x16_bf16(v1, pf, o2[1], 0, 0, 0);
            }
            __builtin_amdgcn_s_setprio(0);
        }
        // no trailing drain: next iteration's vmcnt(4)+barrier gates reuse
    }

    // drain in-flight clamped tail prefetches before endpgm (R5 lesson)
    asm volatile("s_waitcnt vmcnt(0)" ::: "memory");

    // epilogue: combine the hi-pair's l partials once; 8x 8B stores per lane
    float l_full = l_i + __shfl_xor(l_i, 32, 64);
    float rl = 1.0f / l_full;
    unsigned short* orow = &obuf[((size_t)(b * S_LEN + qg)) * EMBD + h * HDIM];
#pragma unroll
    for (int t2 = 0; t2 < 2; ++t2)
#pragma unroll
        for (int u = 0; u < 4; ++u) {
            uint2 pw;
            pw.x = pkbf(o2[t2][4 * u] * rl,     o2[t2][4 * u + 1] * rl);
            pw.y = pkbf(o2[t2][4 * u + 2] * rl, o2[t2][4 * u + 3] * rl);
            *(uint2*)&orow[t2 * 32 + 4 * hi + 8 * u] = pw;
        }
}

extern "C" void kernel_launch(void* const* d_in, const int* in_sizes, int n_in,
                              void* d_out, int out_size, void* d_ws, size_t ws_size,
                              hipStream_t stream) {
    const float* hidden = (const float*)d_in[0];  // [2,2048,1024]
    const float* w_attn = (const float*)d_in[1];  // [3072,1024]
    const float* b_attn = (const float*)d_in[2];  // [3072]
    const float* w_proj = (const float*)d_in[3];  // [1024,1024]
    const float* b_proj = (const float*)d_in[4];  // [1024]
    float* out = (float*)d_out;                   // [2,2048,1024] fp32

    unsigned short* Xbf  = (unsigned short*)d_ws;          // 4096*1024
    unsigned short* Wabf = Xbf  + (size_t)ROWS * EMBD;     // 3072*1024
    unsigned short* Wpbf = Wabf + (size_t)3 * EMBD * EMBD; // 1024*1024
    unsigned short* qb   = Wpbf + (size_t)EMBD * EMBD;     // [B,H,S,D] (q pre-scaled)
    unsigned short* kb   = qb + (size_t)BATCHN * NHEAD * S_LEN * HDIM;
    unsigned short* vtb  = kb + (size_t)BATCHN * NHEAD * S_LEN * HDIM; // [B,H,D,S]
    unsigned short* ob   = vtb + (size_t)BATCHN * NHEAD * S_LEN * HDIM; // [B,S,E]

    // fp32 -> bf16 converts (single launch; dsts contiguous in ws)
    const int n0   = ROWS * EMBD;
    const int n01  = n0 + 3 * EMBD * EMBD;
    const int ntot = n01 + EMBD * EMBD;
    cvt3_f32_bf16<<<2048, 256, 0, stream>>>(hidden, w_attn, w_proj, Xbf,
                                            n0, n01, ntot);

    // QKV projection: q (pre-scaled), k, V^T
    gemm_bt<1><<<dim3(ROWS / 128, 3 * EMBD / 128), 256, 0, stream>>>(
        Xbf, Wabf, b_attn, nullptr, qb, kb, vtb, ROWS, 3 * EMBD, EMBD);

    // causal attention: 256 blocks x 8 waves, pair-in-block, KVBLK=128
    attn_kernel<<<dim3(256), 512, 0, stream>>>(qb, kb, vtb, ob);

    // output projection -> fp32 out
    gemm_bt<0><<<dim3(ROWS / 128, EMBD / 128), 256, 0, stream>>>(
        ob, Wpbf, b_proj, out, nullptr, nullptr, nullptr, ROWS, EMBD, EMBD);
}